// Round 5
// baseline (42.125 us; speedup 1.0000x reference)
//
#include <hip/hip_runtime.h>
#include <math.h>

// Problem constants: B=8, P=512, G=128, C=68
#define B_ 8
#define P_ 512
#define G_ 128
#define C_ 68
#define BG (B_ * G_)   // 1024
#define BP (B_ * P_)   // 4096
#define EPS_ 1.0f      // AABB slack: excluded pairs have >1px gap -> exact 0 in ref

// One 64-thread block (1 wave) per (b,g):
//  - gt prep (CCW, degenerate, AABB) in registers
//  - 8 preds/lane AABB scan (inline pred AABB + degenerate fold),
//    ballot+mbcnt compaction -> LDS survivor list (deterministic order)
//  - survivors clipped (Sutherland-Hodgman, LDS [pt][64], conflict-free)
//  - wave shuffle (area, min-idx) argmax
//  - wave-parallel 68-wide log-softmax CE
//  - lane 0 accumulates directly into out[3] with device-coherent atomics
//    (NO threadfence: memory-side atomics are device-scope on their own;
//     round-4 showed per-block __threadfence costs ~25us in L2 writebacks)
__global__ __launch_bounds__(64) void match_kernel(
    const float* __restrict__ bboxes,   // [BP,9]
    const float* __restrict__ scores,   // [BP,C]
    const float* __restrict__ polys,    // [BG,4,2]
    const int*   __restrict__ labels,   // [BG]
    float* __restrict__ out)            // [3], zeroed by memsetAsync
{
#pragma clang fp contract(off)
    const int bg = blockIdx.x;
    const int b  = bg >> 7;            // / G_
    const int t  = threadIdx.x;

    __shared__ int   s_idx[P_];
    __shared__ float s_px[8 * 64], s_py[8 * 64];
    __shared__ float s_qx[8 * 64], s_qy[8 * 64];

    // ---- gt prep (bit-identical to validated rounds) ----
    const float* cp = polys + (size_t)bg * 8;
    const float x0 = cp[0], y0 = cp[1], x1 = cp[2], y1 = cp[3];
    const float x2 = cp[4], y2 = cp[5], x3 = cp[6], y3 = cp[7];
    const float sa = (x0 * y1 - x1 * y0) + (x1 * y2 - x2 * y1)
                   + (x2 * y3 - x3 * y2) + (x3 * y0 - x0 * y3);
    const bool rev = (sa < 0.0f);
    float ccx[4], ccy[4];
    ccx[0] = rev ? x3 : x0; ccy[0] = rev ? y3 : y0;
    ccx[1] = rev ? x2 : x1; ccy[1] = rev ? y2 : y1;
    ccx[2] = rev ? x1 : x2; ccy[2] = rev ? y1 : y2;
    ccx[3] = rev ? x0 : x3; ccy[3] = rev ? y0 : y3;
    const bool gt_deg =
        (x0 == x1 && y0 == y1) || (x0 == x2 && y0 == y2) ||
        (x0 == x3 && y0 == y3) || (x1 == x2 && y1 == y2) ||
        (x1 == x3 && y1 == y3) || (x2 == x3 && y2 == y3);
    const float glox = fminf(fminf(x0, x1), fminf(x2, x3)) - EPS_;
    const float gloy = fminf(fminf(y0, y1), fminf(y2, y3)) - EPS_;
    const float ghix = fmaxf(fmaxf(x0, x1), fmaxf(x2, x3)) + EPS_;
    const float ghiy = fmaxf(fmaxf(y0, y1), fmaxf(y2, y3)) + EPS_;

    // ---- AABB scan: 8 preds per lane, ballot-prefix compaction ----
    const float* bbb = bboxes + (size_t)b * P_ * 9;
    int base = 0;
    #pragma unroll
    for (int r = 0; r < 8; ++r) {
        const int p = t + (r << 6);
        const float* bb = bbb + (size_t)p * 9;
        const float a0 = bb[0], a1 = bb[1], a2 = bb[2], a3 = bb[3];
        const float a4 = bb[4], a5 = bb[5], a6 = bb[6], a7 = bb[7];
        const bool deg =
            (a0 == a2 && a1 == a3) || (a0 == a4 && a1 == a5) ||
            (a0 == a6 && a1 == a7) || (a2 == a4 && a3 == a5) ||
            (a2 == a6 && a3 == a7) || (a4 == a6 && a5 == a7);
        const float lox = fminf(fminf(a0, a2), fminf(a4, a6));
        const float loy = fminf(fminf(a1, a3), fminf(a5, a7));
        const float hix = fmaxf(fmaxf(a0, a2), fmaxf(a4, a6));
        const float hiy = fmaxf(fmaxf(a1, a3), fmaxf(a5, a7));
        const bool ov = !deg &&
            (lox <= ghix) && (glox <= hix) &&
            (loy <= ghiy) && (gloy <= hiy);
        const unsigned long long mask = __ballot(ov);
        if (ov) {
            const int pre = __builtin_amdgcn_mbcnt_hi(
                (unsigned int)(mask >> 32),
                __builtin_amdgcn_mbcnt_lo((unsigned int)mask, 0u));
            s_idx[base + pre] = p;
        }
        base += __popcll(mask);
    }
    const int ns = base;

    // ---- clip survivors (bit-identical SH) ----
    float bestA = 0.0f;
    int   bestI = 0x7fffffff;

    for (int k0 = 0; k0 < ns; k0 += 64) {
        const int k = k0 + t;
        if (k < ns) {
            const int p = s_idx[k];
            const float* bb = bbb + (size_t)p * 9;
            s_px[0 * 64 + t] = bb[0]; s_py[0 * 64 + t] = bb[1];
            s_px[1 * 64 + t] = bb[2]; s_py[1 * 64 + t] = bb[3];
            s_px[2 * 64 + t] = bb[4]; s_py[2 * 64 + t] = bb[5];
            s_px[3 * 64 + t] = bb[6]; s_py[3 * 64 + t] = bb[7];
            int n = 4;
            float* curx = s_px; float* cury = s_py;
            float* outx = s_qx; float* outy = s_qy;
            #pragma unroll
            for (int e = 0; e < 4; ++e) {
                const float eax = ccx[e], eay = ccy[e];
                const float ex = ccx[(e + 1) & 3] - eax;
                const float ey = ccy[(e + 1) & 3] - eay;
                int m = 0;
                for (int i = 0; i < n; ++i) {
                    const int j = (i + 1 == n) ? 0 : i + 1;
                    const float pxi = curx[i * 64 + t], pyi = cury[i * 64 + t];
                    const float pxj = curx[j * 64 + t], pyj = cury[j * 64 + t];
                    const float dp = ex * (pyi - eay) - ey * (pxi - eax);
                    const float dq = ex * (pyj - eay) - ey * (pxj - eax);
                    const bool inp = (dp >= 0.0f);
                    const bool inq = (dq >= 0.0f);
                    if (inp) {
                        if (m < 8) { outx[m * 64 + t] = pxi; outy[m * 64 + t] = pyi; }
                        ++m;
                    }
                    if (inp != inq) {
                        const float den = dp - dq;
                        const float tt = (den == 0.0f) ? 0.0f : dp / den;
                        if (m < 8) {
                            outx[m * 64 + t] = pxi + tt * (pxj - pxi);
                            outy[m * 64 + t] = pyi + tt * (pyj - pyi);
                        }
                        ++m;
                    }
                }
                n = (m > 8) ? 8 : m;
                float* tx = curx; curx = outx; outx = tx;
                float* ty = cury; cury = outy; outy = ty;
            }
            float s = 0.0f;
            for (int i = 0; i < n; ++i) {
                const int j = (i + 1 == n) ? 0 : i + 1;
                s += curx[i * 64 + t] * cury[j * 64 + t]
                   - curx[j * 64 + t] * cury[i * 64 + t];
            }
            const float area = fabsf(0.5f * s);
            if (area > bestA || (area == bestA && p < bestI)) {
                bestA = area; bestI = p;
            }
        }
    }

    #pragma unroll
    for (int off = 32; off; off >>= 1) {
        const float oa = __shfl_xor(bestA, off);
        const int   oi = __shfl_xor(bestI, off);
        if (oa > bestA || (oa == bestA && oi < bestI)) { bestA = oa; bestI = oi; }
    }

    const bool matched = (!gt_deg) && (bestA != 0.0f);
    const int label = labels[bg];

    float ce_val  = 0.0f;
    bool  is_corr = false;

    if (matched) {
        const float* sc = scores + (size_t)(b * P_ + bestI) * C_;
        const float v0 = sc[t];
        const bool  h2 = (t + 64) < C_;
        const float v1 = h2 ? sc[t + 64] : -3e38f;
        float bv; int bi;
        if (v1 > v0) { bv = v1; bi = t + 64; } else { bv = v0; bi = t; }
        float mx = fmaxf(v0, v1);
        #pragma unroll
        for (int off = 32; off; off >>= 1) mx = fmaxf(mx, __shfl_xor(mx, off));
        #pragma unroll
        for (int off = 32; off; off >>= 1) {
            const float ov2 = __shfl_xor(bv, off);
            const int   oi2 = __shfl_xor(bi, off);
            if (ov2 > bv || (ov2 == bv && oi2 < bi)) { bv = ov2; bi = oi2; }
        }
        float e = expf(v0 - mx) + (h2 ? expf(v1 - mx) : 0.0f);
        #pragma unroll
        for (int off = 32; off; off >>= 1) e += __shfl_xor(e, off);
        ce_val  = mx + logf(e) - sc[label];
        is_corr = (bi == label);
    } else {
        ce_val  = logf((float)C_);
        is_corr = false;
    }

    if (t == 0) {
        // out[0]: loss = sum(ce * 2^-10) — scaling by 1/1024 is exact (pow2),
        // atomic-order reassociation error ~1e-6 << 2% threshold.
        atomicAdd(&out[0], ce_val * (1.0f / (float)BG));
        // out[1]: 1024 blocks x 1.0 -> exactly 1024.0
        atomicAdd(&out[1], 1.0f);
        // out[2]: exact integer count (< 2^24)
        if (is_corr) atomicAdd(&out[2], 1.0f);
    }
}

extern "C" void kernel_launch(void* const* d_in, const int* in_sizes, int n_in,
                              void* d_out, int out_size, void* d_ws, size_t ws_size,
                              hipStream_t stream) {
    const float* bboxes = (const float*)d_in[0];   // [B,P,9]
    const float* scores = (const float*)d_in[1];   // [B,P,C]
    const float* polys  = (const float*)d_in[2];   // [B,G,4,2]
    const int*   labels = (const int*)d_in[3];     // [B,G]
    float* out = (float*)d_out;

    // out is poisoned once and never re-poisoned between replays; we
    // accumulate atomically, so zero it at the head of every launch.
    hipMemsetAsync(out, 0, 3 * sizeof(float), stream);
    match_kernel<<<BG, 64, 0, stream>>>(bboxes, scores, polys, labels, out);
}

// Round 7
// 18.366 us; speedup vs baseline: 2.2937x; 2.2937x over previous
//
#include <hip/hip_runtime.h>
#include <math.h>

// Problem constants: B=8, P=512, G=128, C=68
#define B_ 8
#define P_ 512
#define G_ 128
#define C_ 68
#define BG (B_ * G_)   // 1024
#define BP (B_ * P_)   // 4096
#define NB 128         // blocks; 8 waves/block, one (b,g) per wave
#define EPS_ 1.0f      // AABB slack: excluded pairs have >1px gap -> exact 0 in ref

// Single kernel, single graph node.
// Block blk (512 thr, 8 waves) serves batch b = blk>>4; wave w -> bg = blk*8+w.
//  - stage: 512 pred AABBs (deg-folded/inverted) into LDS, 1 pred/thread
//  - per wave: gt prep -> LDS AABB scan + ballot compaction -> SH clip (LDS
//    [pt][64], conflict-free) -> shuffle argmax -> 68-wide log-softmax CE
//  - block partial (fixed-order 8-sum) -> slots[blk] plain store
//  - handoff: __threadfence() release -> counter ticket; winner
//    ((ticket&127)==127: works from ANY initial counter value, every replay,
//    2^32%128==0) -> __threadfence() acquire -> volatile reads -> fixed-tree
//    reduce (bitwise deterministic regardless of which block wins).
//  Round-4 proved this fence pattern correct; round-6 proved the fenceless
//  variant flaky. At 128 blocks the fence+atomic cost is ~1/8 of round 4's.
__global__ __launch_bounds__(512) void fused_kernel(
    const float* __restrict__ bboxes,   // [BP,9]
    const float* __restrict__ scores,   // [BP,C]
    const float* __restrict__ polys,    // [BG,4,2]
    const int*   __restrict__ labels,   // [BG]
    unsigned long long* __restrict__ slots,  // [NB] ws (no init needed)
    unsigned int* __restrict__ counter,      // [1] ws (any value OK)
    float* __restrict__ out)            // [3]
{
#pragma clang fp contract(off)
    const int blk  = blockIdx.x;        // 0..127
    const int t    = threadIdx.x;       // 0..511
    const int w    = t >> 6;            // wave 0..7
    const int lane = t & 63;
    const int bg   = (blk << 3) | w;    // 0..1023
    const int b    = bg >> 7;           // batch (uniform per block)

    __shared__ float s_lx[P_], s_ly[P_], s_hx[P_], s_hy[P_];  // pred AABBs
    __shared__ int   s_idx[8 * P_];                           // per-wave lists
    __shared__ float s_px[8 * 512], s_py[8 * 512];            // clip buf A
    __shared__ float s_qx[8 * 512], s_qy[8 * 512];            // clip buf B
    __shared__ float s_ce[8];
    __shared__ int   s_co[8];
    __shared__ int   s_last;

    const float* bbb = bboxes + (size_t)b * P_ * 9;

    // ---- stage pred AABBs (bit-identical expressions to validated rounds) ----
    {
        const int p = t;                 // 512 threads, 512 preds
        const float* bb = bbb + (size_t)p * 9;
        const float a0 = bb[0], a1 = bb[1], a2 = bb[2], a3 = bb[3];
        const float a4 = bb[4], a5 = bb[5], a6 = bb[6], a7 = bb[7];
        const bool deg =
            (a0 == a2 && a1 == a3) || (a0 == a4 && a1 == a5) ||
            (a0 == a6 && a1 == a7) || (a2 == a4 && a3 == a5) ||
            (a2 == a6 && a3 == a7) || (a4 == a6 && a5 == a7);
        float lox = fminf(fminf(a0, a2), fminf(a4, a6));
        float loy = fminf(fminf(a1, a3), fminf(a5, a7));
        float hix = fmaxf(fmaxf(a0, a2), fmaxf(a4, a6));
        float hiy = fmaxf(fmaxf(a1, a3), fmaxf(a5, a7));
        if (deg) { lox = 3e38f; loy = 3e38f; hix = -3e38f; hiy = -3e38f; }
        s_lx[p] = lox; s_ly[p] = loy; s_hx[p] = hix; s_hy[p] = hiy;
    }
    __syncthreads();

    int*   widx = s_idx + (w << 9);
    float* wpx  = s_px  + (w << 9);
    float* wpy  = s_py  + (w << 9);
    float* wqx  = s_qx  + (w << 9);
    float* wqy  = s_qy  + (w << 9);

    // ---- gt prep (bit-identical) ----
    const float* cp = polys + (size_t)bg * 8;
    const float x0 = cp[0], y0 = cp[1], x1 = cp[2], y1 = cp[3];
    const float x2 = cp[4], y2 = cp[5], x3 = cp[6], y3 = cp[7];
    const float sa = (x0 * y1 - x1 * y0) + (x1 * y2 - x2 * y1)
                   + (x2 * y3 - x3 * y2) + (x3 * y0 - x0 * y3);
    const bool rev = (sa < 0.0f);
    float ccx[4], ccy[4];
    ccx[0] = rev ? x3 : x0; ccy[0] = rev ? y3 : y0;
    ccx[1] = rev ? x2 : x1; ccy[1] = rev ? y2 : y1;
    ccx[2] = rev ? x1 : x2; ccy[2] = rev ? y1 : y2;
    ccx[3] = rev ? x0 : x3; ccy[3] = rev ? y0 : y3;
    const bool gt_deg =
        (x0 == x1 && y0 == y1) || (x0 == x2 && y0 == y2) ||
        (x0 == x3 && y0 == y3) || (x1 == x2 && y1 == y2) ||
        (x1 == x3 && y1 == y3) || (x2 == x3 && y2 == y3);
    const float glox = fminf(fminf(x0, x1), fminf(x2, x3)) - EPS_;
    const float gloy = fminf(fminf(y0, y1), fminf(y2, y3)) - EPS_;
    const float ghix = fmaxf(fmaxf(x0, x1), fmaxf(x2, x3)) + EPS_;
    const float ghiy = fmaxf(fmaxf(y0, y1), fmaxf(y2, y3)) + EPS_;

    // ---- AABB scan from LDS: 8 preds/lane, ballot-prefix compaction ----
    int base = 0;
    #pragma unroll
    for (int r = 0; r < 8; ++r) {
        const int p = lane + (r << 6);
        const bool ov =
            (s_lx[p] <= ghix) && (glox <= s_hx[p]) &&
            (s_ly[p] <= ghiy) && (gloy <= s_hy[p]);
        const unsigned long long mask = __ballot(ov);
        if (ov) {
            const int pre = __builtin_amdgcn_mbcnt_hi(
                (unsigned int)(mask >> 32),
                __builtin_amdgcn_mbcnt_lo((unsigned int)mask, 0u));
            widx[base + pre] = p;
        }
        base += __popcll(mask);
    }
    const int ns = base;

    // ---- clip survivors (bit-identical SH, LDS [pt][64] per wave) ----
    float bestA = 0.0f;
    int   bestI = 0x7fffffff;

    for (int k0 = 0; k0 < ns; k0 += 64) {
        const int k = k0 + lane;
        if (k < ns) {
            const int p = widx[k];
            const float* bb = bbb + (size_t)p * 9;
            wpx[0 * 64 + lane] = bb[0]; wpy[0 * 64 + lane] = bb[1];
            wpx[1 * 64 + lane] = bb[2]; wpy[1 * 64 + lane] = bb[3];
            wpx[2 * 64 + lane] = bb[4]; wpy[2 * 64 + lane] = bb[5];
            wpx[3 * 64 + lane] = bb[6]; wpy[3 * 64 + lane] = bb[7];
            int n = 4;
            float* curx = wpx; float* cury = wpy;
            float* outx = wqx; float* outy = wqy;
            #pragma unroll
            for (int e = 0; e < 4; ++e) {
                const float eax = ccx[e], eay = ccy[e];
                const float ex = ccx[(e + 1) & 3] - eax;
                const float ey = ccy[(e + 1) & 3] - eay;
                int m = 0;
                for (int i = 0; i < n; ++i) {
                    const int j = (i + 1 == n) ? 0 : i + 1;
                    const float pxi = curx[i * 64 + lane], pyi = cury[i * 64 + lane];
                    const float pxj = curx[j * 64 + lane], pyj = cury[j * 64 + lane];
                    const float dp = ex * (pyi - eay) - ey * (pxi - eax);
                    const float dq = ex * (pyj - eay) - ey * (pxj - eax);
                    const bool inp = (dp >= 0.0f);
                    const bool inq = (dq >= 0.0f);
                    if (inp) {
                        if (m < 8) { outx[m * 64 + lane] = pxi; outy[m * 64 + lane] = pyi; }
                        ++m;
                    }
                    if (inp != inq) {
                        const float den = dp - dq;
                        const float tt = (den == 0.0f) ? 0.0f : dp / den;
                        if (m < 8) {
                            outx[m * 64 + lane] = pxi + tt * (pxj - pxi);
                            outy[m * 64 + lane] = pyi + tt * (pyj - pyi);
                        }
                        ++m;
                    }
                }
                n = (m > 8) ? 8 : m;
                float* tx = curx; curx = outx; outx = tx;
                float* ty = cury; cury = outy; outy = ty;
            }
            float s = 0.0f;
            for (int i = 0; i < n; ++i) {
                const int j = (i + 1 == n) ? 0 : i + 1;
                s += curx[i * 64 + lane] * cury[j * 64 + lane]
                   - curx[j * 64 + lane] * cury[i * 64 + lane];
            }
            const float area = fabsf(0.5f * s);
            if (area > bestA || (area == bestA && p < bestI)) {
                bestA = area; bestI = p;
            }
        }
    }

    #pragma unroll
    for (int off = 32; off; off >>= 1) {
        const float oa = __shfl_xor(bestA, off);
        const int   oi = __shfl_xor(bestI, off);
        if (oa > bestA || (oa == bestA && oi < bestI)) { bestA = oa; bestI = oi; }
    }

    const bool matched = (!gt_deg) && (bestA != 0.0f);
    const int label = labels[bg];

    float ce_val  = 0.0f;
    bool  is_corr = false;

    if (matched) {
        const float* sc = scores + (size_t)(b * P_ + bestI) * C_;
        const float v0 = sc[lane];
        const bool  h2 = (lane + 64) < C_;
        const float v1 = h2 ? sc[lane + 64] : -3e38f;
        float bv; int bi;
        if (v1 > v0) { bv = v1; bi = lane + 64; } else { bv = v0; bi = lane; }
        float mx = fmaxf(v0, v1);
        #pragma unroll
        for (int off = 32; off; off >>= 1) mx = fmaxf(mx, __shfl_xor(mx, off));
        #pragma unroll
        for (int off = 32; off; off >>= 1) {
            const float ov2 = __shfl_xor(bv, off);
            const int   oi2 = __shfl_xor(bi, off);
            if (ov2 > bv || (ov2 == bv && oi2 < bi)) { bv = ov2; bi = oi2; }
        }
        float e = expf(v0 - mx) + (h2 ? expf(v1 - mx) : 0.0f);
        #pragma unroll
        for (int off = 32; off; off >>= 1) e += __shfl_xor(e, off);
        ce_val  = mx + logf(e) - sc[label];
        is_corr = (bi == label);
    } else {
        ce_val  = logf((float)C_);
        is_corr = false;
    }

    if (lane == 0) {
        s_ce[w] = ce_val;
        s_co[w] = is_corr ? 1 : 0;
    }
    __syncthreads();

    if (t == 0) {
        // fixed-order block partial (bitwise deterministic)
        float a = 0.0f; int c = 0;
        #pragma unroll
        for (int i = 0; i < 8; ++i) { a += s_ce[i]; c += s_co[i]; }
        const unsigned long long pack =
            ((unsigned long long)__float_as_uint(a) << 32) | (unsigned int)c;
        *(volatile unsigned long long*)&slots[blk] = pack;
        __threadfence();                         // release (round-4-proven)
        const unsigned int tic = atomicAdd(counter, 1u);
        s_last = ((tic & (unsigned)(NB - 1)) == (unsigned)(NB - 1)) ? 1 : 0;
    }
    __syncthreads();

    if (s_last) {
        __threadfence();                         // acquire
        float fa = 0.0f; int fc = 0;
        if (t < NB) {
            const unsigned long long v = *(volatile const unsigned long long*)&slots[t];
            fa = __uint_as_float((unsigned int)(v >> 32));
            fc = (int)(unsigned int)(v & 0xffffffffULL);
            #pragma unroll
            for (int off = 32; off; off >>= 1) {
                fa += __shfl_xor(fa, off);
                fc += __shfl_xor(fc, off);
            }
        }
        __shared__ float ra[2];
        __shared__ int   rc[2];
        if (t < NB && lane == 0) { ra[w] = fa; rc[w] = fc; }
        __syncthreads();
        if (t == 0) {
            out[0] = (ra[0] + ra[1]) * (1.0f / (float)BG);  // mean ce
            out[1] = (float)BG;                             // total_number
            out[2] = (float)(rc[0] + rc[1]);                // rec_correct
        }
    }
}

extern "C" void kernel_launch(void* const* d_in, const int* in_sizes, int n_in,
                              void* d_out, int out_size, void* d_ws, size_t ws_size,
                              hipStream_t stream) {
    const float* bboxes = (const float*)d_in[0];   // [B,P,9]
    const float* scores = (const float*)d_in[1];   // [B,P,C]
    const float* polys  = (const float*)d_in[2];   // [B,G,4,2]
    const int*   labels = (const int*)d_in[3];     // [B,G]
    float* out = (float*)d_out;

    unsigned long long* slots   = (unsigned long long*)d_ws;          // [NB]
    unsigned int*       counter = (unsigned int*)((char*)d_ws + 4096);

    fused_kernel<<<NB, 512, 0, stream>>>(bboxes, scores, polys, labels,
                                         slots, counter, out);
}

// Round 8
// 16.587 us; speedup vs baseline: 2.5397x; 1.1072x over previous
//
#include <hip/hip_runtime.h>
#include <math.h>

// Problem constants: B=8, P=512, G=128, C=68
#define B_ 8
#define P_ 512
#define G_ 128
#define C_ 68
#define BG (B_ * G_)   // 1024
#define BP (B_ * P_)   // 4096
#define EPS_ 1.0f      // AABB slack: excluded pairs have >1px gap -> exact 0 in ref

// One 64-thread block (1 wave) per (b,g). Round-3 structure (best: 17.9us),
// with the Sutherland-Hodgman clip rewritten as fixed-bound predicated
// unroll: per edge, all 8 vertices batch-read from LDS into registers
// (one LDS latency instead of ~6 dependent ones), dq/q selected from
// already-computed dp[] via cndmask (bit-identical values), edge 0 fully
// in registers. FP expressions and emission order unchanged from the
// absmax-0.0-validated kernel.
//
// CLIP_EDGE: reads polygon from INX/INY (LDS), writes clipped to OUTX/OUTY.
#define CLIP_EDGE(E, INX, INY, OUTX, OUTY)                                   \
    {                                                                        \
        const float eax = ccx[E], eay = ccy[E];                              \
        const float ex = ccx[(E + 1) & 3] - eax;                             \
        const float ey = ccy[(E + 1) & 3] - eay;                             \
        float vx[8], vy[8], dp[8];                                           \
        bool  vin[8];                                                        \
        _Pragma("unroll")                                                    \
        for (int i = 0; i < 8; ++i) {                                        \
            vx[i] = INX[i * 64 + t];                                         \
            vy[i] = INY[i * 64 + t];                                         \
        }                                                                    \
        _Pragma("unroll")                                                    \
        for (int i = 0; i < 8; ++i) {                                        \
            dp[i]  = ex * (vy[i] - eay) - ey * (vx[i] - eax);                \
            vin[i] = (dp[i] >= 0.0f);                                        \
        }                                                                    \
        int m = 0;                                                           \
        _Pragma("unroll")                                                    \
        for (int i = 0; i < 8; ++i) {                                        \
            if (i < n) {                                                     \
                const bool wrap = (i + 1 == n);                              \
                const int  jn   = (i + 1) & 7;                               \
                const float qx = wrap ? vx[0] : vx[jn];                      \
                const float qy = wrap ? vy[0] : vy[jn];                      \
                const float dq = wrap ? dp[0] : dp[jn];                      \
                const bool  inq = (dq >= 0.0f);                              \
                if (vin[i]) {                                                \
                    if (m < 8) { OUTX[m * 64 + t] = vx[i];                   \
                                 OUTY[m * 64 + t] = vy[i]; }                 \
                    ++m;                                                     \
                }                                                            \
                if (vin[i] != inq) {                                         \
                    const float den = dp[i] - dq;                            \
                    const float tt = (den == 0.0f) ? 0.0f : dp[i] / den;     \
                    if (m < 8) {                                             \
                        OUTX[m * 64 + t] = vx[i] + tt * (qx - vx[i]);        \
                        OUTY[m * 64 + t] = vy[i] + tt * (qy - vy[i]);        \
                    }                                                        \
                    ++m;                                                     \
                }                                                            \
            }                                                                \
        }                                                                    \
        n = (m > 8) ? 8 : m;                                                 \
    }

__global__ __launch_bounds__(64) void match_kernel(
    const float* __restrict__ bboxes,   // [BP,9]
    const float* __restrict__ scores,   // [BP,C]
    const float* __restrict__ polys,    // [BG,4,2]
    const int*   __restrict__ labels,   // [BG]
    float* __restrict__ ce_out,         // [BG]
    int*   __restrict__ corr_out)       // [BG]
{
#pragma clang fp contract(off)
    const int bg = blockIdx.x;
    const int b  = bg >> 7;            // / G_
    const int t  = threadIdx.x;

    __shared__ int   s_idx[P_];
    __shared__ float s_px[8 * 64], s_py[8 * 64];
    __shared__ float s_qx[8 * 64], s_qy[8 * 64];

    // ---- gt prep (bit-identical to validated rounds) ----
    const float* cp = polys + (size_t)bg * 8;
    const float x0 = cp[0], y0 = cp[1], x1 = cp[2], y1 = cp[3];
    const float x2 = cp[4], y2 = cp[5], x3 = cp[6], y3 = cp[7];
    const float sa = (x0 * y1 - x1 * y0) + (x1 * y2 - x2 * y1)
                   + (x2 * y3 - x3 * y2) + (x3 * y0 - x0 * y3);
    const bool rev = (sa < 0.0f);
    float ccx[4], ccy[4];
    ccx[0] = rev ? x3 : x0; ccy[0] = rev ? y3 : y0;
    ccx[1] = rev ? x2 : x1; ccy[1] = rev ? y2 : y1;
    ccx[2] = rev ? x1 : x2; ccy[2] = rev ? y1 : y2;
    ccx[3] = rev ? x0 : x3; ccy[3] = rev ? y0 : y3;
    const bool gt_deg =
        (x0 == x1 && y0 == y1) || (x0 == x2 && y0 == y2) ||
        (x0 == x3 && y0 == y3) || (x1 == x2 && y1 == y2) ||
        (x1 == x3 && y1 == y3) || (x2 == x3 && y2 == y3);
    const float glox = fminf(fminf(x0, x1), fminf(x2, x3)) - EPS_;
    const float gloy = fminf(fminf(y0, y1), fminf(y2, y3)) - EPS_;
    const float ghix = fmaxf(fmaxf(x0, x1), fmaxf(x2, x3)) + EPS_;
    const float ghiy = fmaxf(fmaxf(y0, y1), fmaxf(y2, y3)) + EPS_;

    // ---- AABB scan: 8 preds per lane, ballot-prefix compaction ----
    const float* bbb = bboxes + (size_t)b * P_ * 9;
    int base = 0;
    #pragma unroll
    for (int r = 0; r < 8; ++r) {
        const int p = t + (r << 6);
        const float* bb = bbb + (size_t)p * 9;
        const float a0 = bb[0], a1 = bb[1], a2 = bb[2], a3 = bb[3];
        const float a4 = bb[4], a5 = bb[5], a6 = bb[6], a7 = bb[7];
        const bool deg =
            (a0 == a2 && a1 == a3) || (a0 == a4 && a1 == a5) ||
            (a0 == a6 && a1 == a7) || (a2 == a4 && a3 == a5) ||
            (a2 == a6 && a3 == a7) || (a4 == a6 && a5 == a7);
        const float lox = fminf(fminf(a0, a2), fminf(a4, a6));
        const float loy = fminf(fminf(a1, a3), fminf(a5, a7));
        const float hix = fmaxf(fmaxf(a0, a2), fmaxf(a4, a6));
        const float hiy = fmaxf(fmaxf(a1, a3), fmaxf(a5, a7));
        const bool ov = !deg &&
            (lox <= ghix) && (glox <= hix) &&
            (loy <= ghiy) && (gloy <= hiy);
        const unsigned long long mask = __ballot(ov);
        if (ov) {
            const int pre = __builtin_amdgcn_mbcnt_hi(
                (unsigned int)(mask >> 32),
                __builtin_amdgcn_mbcnt_lo((unsigned int)mask, 0u));
            s_idx[base + pre] = p;
        }
        base += __popcll(mask);
    }
    const int ns = base;

    // ---- clip survivors: fixed-bound predicated unroll ----
    float bestA = 0.0f;
    int   bestI = 0x7fffffff;

    for (int k0 = 0; k0 < ns; k0 += 64) {
        const int k = k0 + t;
        if (k < ns) {
            const int p = s_idx[k];
            const float* bb = bbb + (size_t)p * 9;
            int n = 4;

            // edge 0: subject quad in registers, n == 4 static
            {
                float vx[4], vy[4], dp[4];
                bool  vin[4];
                vx[0] = bb[0]; vy[0] = bb[1];
                vx[1] = bb[2]; vy[1] = bb[3];
                vx[2] = bb[4]; vy[2] = bb[5];
                vx[3] = bb[6]; vy[3] = bb[7];
                const float eax = ccx[0], eay = ccy[0];
                const float ex = ccx[1] - eax;
                const float ey = ccy[1] - eay;
                #pragma unroll
                for (int i = 0; i < 4; ++i) {
                    dp[i]  = ex * (vy[i] - eay) - ey * (vx[i] - eax);
                    vin[i] = (dp[i] >= 0.0f);
                }
                int m = 0;
                #pragma unroll
                for (int i = 0; i < 4; ++i) {
                    const int j = (i + 1) & 3;
                    if (vin[i]) {
                        if (m < 8) { s_qx[m * 64 + t] = vx[i];
                                     s_qy[m * 64 + t] = vy[i]; }
                        ++m;
                    }
                    if (vin[i] != vin[j]) {
                        const float den = dp[i] - dp[j];
                        const float tt = (den == 0.0f) ? 0.0f : dp[i] / den;
                        if (m < 8) {
                            s_qx[m * 64 + t] = vx[i] + tt * (vx[j] - vx[i]);
                            s_qy[m * 64 + t] = vy[i] + tt * (vy[j] - vy[i]);
                        }
                        ++m;
                    }
                }
                n = (m > 8) ? 8 : m;
            }

            CLIP_EDGE(1, s_qx, s_qy, s_px, s_py)
            CLIP_EDGE(2, s_px, s_py, s_qx, s_qy)
            CLIP_EDGE(3, s_qx, s_qy, s_px, s_py)

            // shoelace on final polygon (in s_px/s_py), predicated unroll
            float s = 0.0f;
            {
                float vx[8], vy[8];
                #pragma unroll
                for (int i = 0; i < 8; ++i) {
                    vx[i] = s_px[i * 64 + t];
                    vy[i] = s_py[i * 64 + t];
                }
                #pragma unroll
                for (int i = 0; i < 8; ++i) {
                    if (i < n) {
                        const bool wrap = (i + 1 == n);
                        const int  jn   = (i + 1) & 7;
                        const float qx = wrap ? vx[0] : vx[jn];
                        const float qy = wrap ? vy[0] : vy[jn];
                        s += vx[i] * qy - qx * vy[i];
                    }
                }
            }
            const float area = fabsf(0.5f * s);
            if (area > bestA || (area == bestA && p < bestI)) {
                bestA = area; bestI = p;
            }
        }
    }

    // 64-lane (area, min-idx) reduce — order-independent, deterministic
    #pragma unroll
    for (int off = 32; off; off >>= 1) {
        const float oa = __shfl_xor(bestA, off);
        const int   oi = __shfl_xor(bestI, off);
        if (oa > bestA || (oa == bestA && oi < bestI)) { bestA = oa; bestI = oi; }
    }

    const bool matched = (!gt_deg) && (bestA != 0.0f);
    const int label = labels[bg];

    if (matched) {
        const float* sc = scores + (size_t)(b * P_ + bestI) * C_;
        const float v0 = sc[t];
        const bool  h2 = (t + 64) < C_;
        const float v1 = h2 ? sc[t + 64] : -3e38f;
        float bv; int bi;
        if (v1 > v0) { bv = v1; bi = t + 64; } else { bv = v0; bi = t; }
        float mx = fmaxf(v0, v1);
        #pragma unroll
        for (int off = 32; off; off >>= 1) mx = fmaxf(mx, __shfl_xor(mx, off));
        #pragma unroll
        for (int off = 32; off; off >>= 1) {
            const float ov2 = __shfl_xor(bv, off);
            const int   oi2 = __shfl_xor(bi, off);
            if (ov2 > bv || (ov2 == bv && oi2 < bi)) { bv = ov2; bi = oi2; }
        }
        float e = expf(v0 - mx) + (h2 ? expf(v1 - mx) : 0.0f);
        #pragma unroll
        for (int off = 32; off; off >>= 1) e += __shfl_xor(e, off);
        if (t == 0) {
            ce_out[bg]   = mx + logf(e) - sc[label];
            corr_out[bg] = (bi == label) ? 1 : 0;
        }
    } else {
        if (t == 0) {
            ce_out[bg]   = logf((float)C_);
            corr_out[bg] = 0;
        }
    }
}

// Finalize: deterministic fixed-tree reduction of 1024 (ce, corr) pairs.
__global__ __launch_bounds__(256) void finalize_kernel(
    const float* __restrict__ ce,
    const int*   __restrict__ corr,
    float* __restrict__ out)
{
    const int t = threadIdx.x;
    float a = ce[t] + ce[t + 256] + ce[t + 512] + ce[t + 768];
    int   c = corr[t] + corr[t + 256] + corr[t + 512] + corr[t + 768];
    #pragma unroll
    for (int off = 32; off; off >>= 1) {
        a += __shfl_xor(a, off);
        c += __shfl_xor(c, off);
    }
    __shared__ float pa[4];
    __shared__ int   pc[4];
    if ((t & 63) == 0) { pa[t >> 6] = a; pc[t >> 6] = c; }
    __syncthreads();
    if (t == 0) {
        const float s = (pa[0] + pa[1]) + (pa[2] + pa[3]);
        const int  cc = (pc[0] + pc[1]) + (pc[2] + pc[3]);
        out[0] = s / (float)BG;   // mean ce
        out[1] = (float)BG;       // total_number
        out[2] = (float)cc;       // rec_correct
    }
}

extern "C" void kernel_launch(void* const* d_in, const int* in_sizes, int n_in,
                              void* d_out, int out_size, void* d_ws, size_t ws_size,
                              hipStream_t stream) {
    const float* bboxes = (const float*)d_in[0];   // [B,P,9]
    const float* scores = (const float*)d_in[1];   // [B,P,C]
    const float* polys  = (const float*)d_in[2];   // [B,G,4,2]
    const int*   labels = (const int*)d_in[3];     // [B,G]
    float* out = (float*)d_out;

    float* ce = (float*)d_ws;                             // [BG]
    int*   cr = (int*)((char*)d_ws + BG * sizeof(float)); // [BG]

    match_kernel<<<BG, 64, 0, stream>>>(bboxes, scores, polys, labels, ce, cr);
    finalize_kernel<<<1, 256, 0, stream>>>(ce, cr, out);
}

// Round 9
// 15.004 us; speedup vs baseline: 2.8077x; 1.1055x over previous
//
#include <hip/hip_runtime.h>
#include <math.h>

// Problem constants: B=8, P=512, G=128, C=68
#define B_ 8
#define P_ 512
#define G_ 128
#define C_ 68
#define BG (B_ * G_)   // 1024
#define BP (B_ * P_)   // 4096
#define EPS_ 1.0f      // AABB slack: excluded pairs have >1px gap -> exact 0 in ref

// One 256-thread block (4 waves) per (b,g):
//  - each wave scans a contiguous 128-pred slice (2 ballot rounds) into a
//    private LDS segment (ascending p within segment; segments concatenate
//    to the SAME ascending-p survivor list as the validated 1-wave kernel)
//  - one barrier; waves 1-3 exit; wave 0 merges counts and clips survivors
//    with the R8-validated dechained CLIP_EDGE (bit-identical FP), then
//    does the 68-wide log-softmax CE.
//  Rationale: R8 ran 1 wave/SIMD (zero latency hiding); 4 waves/block gives
//  16 waves/CU during the scan (the load-latency-dominated phase) and cuts
//  the per-wave serial scan chain 4x.
#define CLIP_EDGE(E, INX, INY, OUTX, OUTY)                                   \
    {                                                                        \
        const float eax = ccx[E], eay = ccy[E];                              \
        const float ex = ccx[(E + 1) & 3] - eax;                             \
        const float ey = ccy[(E + 1) & 3] - eay;                             \
        float vx[8], vy[8], dp[8];                                           \
        bool  vin[8];                                                        \
        _Pragma("unroll")                                                    \
        for (int i = 0; i < 8; ++i) {                                        \
            vx[i] = INX[i * 64 + lane];                                      \
            vy[i] = INY[i * 64 + lane];                                      \
        }                                                                    \
        _Pragma("unroll")                                                    \
        for (int i = 0; i < 8; ++i) {                                        \
            dp[i]  = ex * (vy[i] - eay) - ey * (vx[i] - eax);                \
            vin[i] = (dp[i] >= 0.0f);                                        \
        }                                                                    \
        int m = 0;                                                           \
        _Pragma("unroll")                                                    \
        for (int i = 0; i < 8; ++i) {                                        \
            if (i < n) {                                                     \
                const bool wrap = (i + 1 == n);                              \
                const int  jn   = (i + 1) & 7;                               \
                const float qx = wrap ? vx[0] : vx[jn];                      \
                const float qy = wrap ? vy[0] : vy[jn];                      \
                const float dq = wrap ? dp[0] : dp[jn];                      \
                const bool  inq = (dq >= 0.0f);                              \
                if (vin[i]) {                                                \
                    if (m < 8) { OUTX[m * 64 + lane] = vx[i];                \
                                 OUTY[m * 64 + lane] = vy[i]; }              \
                    ++m;                                                     \
                }                                                            \
                if (vin[i] != inq) {                                         \
                    const float den = dp[i] - dq;                            \
                    const float tt = (den == 0.0f) ? 0.0f : dp[i] / den;     \
                    if (m < 8) {                                             \
                        OUTX[m * 64 + lane] = vx[i] + tt * (qx - vx[i]);     \
                        OUTY[m * 64 + lane] = vy[i] + tt * (qy - vy[i]);     \
                    }                                                        \
                    ++m;                                                     \
                }                                                            \
            }                                                                \
        }                                                                    \
        n = (m > 8) ? 8 : m;                                                 \
    }

__global__ __launch_bounds__(256) void match_kernel(
    const float* __restrict__ bboxes,   // [BP,9]
    const float* __restrict__ scores,   // [BP,C]
    const float* __restrict__ polys,    // [BG,4,2]
    const int*   __restrict__ labels,   // [BG]
    float* __restrict__ ce_out,         // [BG]
    int*   __restrict__ corr_out)       // [BG]
{
#pragma clang fp contract(off)
    const int bg   = blockIdx.x;
    const int b    = bg >> 7;           // / G_
    const int t    = threadIdx.x;       // 0..255
    const int w    = t >> 6;            // wave 0..3
    const int lane = t & 63;

    __shared__ int   s_seg[4 * 128];    // per-wave survivor segments
    __shared__ int   s_cnt[4];
    __shared__ float s_px[8 * 64], s_py[8 * 64];
    __shared__ float s_qx[8 * 64], s_qy[8 * 64];

    // ---- gt prep (bit-identical to validated rounds; all threads) ----
    const float* cp = polys + (size_t)bg * 8;
    const float x0 = cp[0], y0 = cp[1], x1 = cp[2], y1 = cp[3];
    const float x2 = cp[4], y2 = cp[5], x3 = cp[6], y3 = cp[7];
    const float sa = (x0 * y1 - x1 * y0) + (x1 * y2 - x2 * y1)
                   + (x2 * y3 - x3 * y2) + (x3 * y0 - x0 * y3);
    const bool rev = (sa < 0.0f);
    float ccx[4], ccy[4];
    ccx[0] = rev ? x3 : x0; ccy[0] = rev ? y3 : y0;
    ccx[1] = rev ? x2 : x1; ccy[1] = rev ? y2 : y1;
    ccx[2] = rev ? x1 : x2; ccy[2] = rev ? y1 : y2;
    ccx[3] = rev ? x0 : x3; ccy[3] = rev ? y0 : y3;
    const bool gt_deg =
        (x0 == x1 && y0 == y1) || (x0 == x2 && y0 == y2) ||
        (x0 == x3 && y0 == y3) || (x1 == x2 && y1 == y2) ||
        (x1 == x3 && y1 == y3) || (x2 == x3 && y2 == y3);
    const float glox = fminf(fminf(x0, x1), fminf(x2, x3)) - EPS_;
    const float gloy = fminf(fminf(y0, y1), fminf(y2, y3)) - EPS_;
    const float ghix = fmaxf(fmaxf(x0, x1), fmaxf(x2, x3)) + EPS_;
    const float ghiy = fmaxf(fmaxf(y0, y1), fmaxf(y2, y3)) + EPS_;

    // ---- scan: wave w covers preds [w*128, w*128+128), 2 ballot rounds ----
    const float* bbb = bboxes + (size_t)b * P_ * 9;
    {
        int base = 0;
        #pragma unroll
        for (int r = 0; r < 2; ++r) {
            const int p = (w << 7) + (r << 6) + lane;
            const float* bb = bbb + (size_t)p * 9;
            const float a0 = bb[0], a1 = bb[1], a2 = bb[2], a3 = bb[3];
            const float a4 = bb[4], a5 = bb[5], a6 = bb[6], a7 = bb[7];
            const bool deg =
                (a0 == a2 && a1 == a3) || (a0 == a4 && a1 == a5) ||
                (a0 == a6 && a1 == a7) || (a2 == a4 && a3 == a5) ||
                (a2 == a6 && a3 == a7) || (a4 == a6 && a5 == a7);
            const float lox = fminf(fminf(a0, a2), fminf(a4, a6));
            const float loy = fminf(fminf(a1, a3), fminf(a5, a7));
            const float hix = fmaxf(fmaxf(a0, a2), fmaxf(a4, a6));
            const float hiy = fmaxf(fmaxf(a1, a3), fmaxf(a5, a7));
            const bool ov = !deg &&
                (lox <= ghix) && (glox <= hix) &&
                (loy <= ghiy) && (gloy <= hiy);
            const unsigned long long mask = __ballot(ov);
            if (ov) {
                const int pre = __builtin_amdgcn_mbcnt_hi(
                    (unsigned int)(mask >> 32),
                    __builtin_amdgcn_mbcnt_lo((unsigned int)mask, 0u));
                s_seg[(w << 7) + base + pre] = p;
            }
            base += __popcll(mask);
        }
        if (lane == 0) s_cnt[w] = base;
    }
    __syncthreads();

    if (w != 0) return;   // wave 0 only from here; no further barriers

    const int c0 = s_cnt[0], c1 = s_cnt[1], c2 = s_cnt[2], c3 = s_cnt[3];
    const int o1 = c0, o2 = c0 + c1, o3 = c0 + c1 + c2;
    const int ns = o3 + c3;

    // ---- clip survivors (R8-validated dechained SH, bit-identical) ----
    float bestA = 0.0f;
    int   bestI = 0x7fffffff;

    for (int k0 = 0; k0 < ns; k0 += 64) {
        const int k = k0 + lane;
        if (k < ns) {
            // merged list element k (segments concatenated = ascending p)
            const int ws  = (k >= o1 ? 1 : 0) + (k >= o2 ? 1 : 0) + (k >= o3 ? 1 : 0);
            const int off = (k >= o3) ? o3 : ((k >= o2) ? o2 : ((k >= o1) ? o1 : 0));
            const int p   = s_seg[(ws << 7) + (k - off)];
            const float* bb = bbb + (size_t)p * 9;
            int n = 4;

            // edge 0: subject quad in registers, n == 4 static
            {
                float vx[4], vy[4], dp[4];
                bool  vin[4];
                vx[0] = bb[0]; vy[0] = bb[1];
                vx[1] = bb[2]; vy[1] = bb[3];
                vx[2] = bb[4]; vy[2] = bb[5];
                vx[3] = bb[6]; vy[3] = bb[7];
                const float eax = ccx[0], eay = ccy[0];
                const float ex = ccx[1] - eax;
                const float ey = ccy[1] - eay;
                #pragma unroll
                for (int i = 0; i < 4; ++i) {
                    dp[i]  = ex * (vy[i] - eay) - ey * (vx[i] - eax);
                    vin[i] = (dp[i] >= 0.0f);
                }
                int m = 0;
                #pragma unroll
                for (int i = 0; i < 4; ++i) {
                    const int j = (i + 1) & 3;
                    if (vin[i]) {
                        if (m < 8) { s_qx[m * 64 + lane] = vx[i];
                                     s_qy[m * 64 + lane] = vy[i]; }
                        ++m;
                    }
                    if (vin[i] != vin[j]) {
                        const float den = dp[i] - dp[j];
                        const float tt = (den == 0.0f) ? 0.0f : dp[i] / den;
                        if (m < 8) {
                            s_qx[m * 64 + lane] = vx[i] + tt * (vx[j] - vx[i]);
                            s_qy[m * 64 + lane] = vy[i] + tt * (vy[j] - vy[i]);
                        }
                        ++m;
                    }
                }
                n = (m > 8) ? 8 : m;
            }

            CLIP_EDGE(1, s_qx, s_qy, s_px, s_py)
            CLIP_EDGE(2, s_px, s_py, s_qx, s_qy)
            CLIP_EDGE(3, s_qx, s_qy, s_px, s_py)

            // shoelace on final polygon (in s_px/s_py), predicated unroll
            float s = 0.0f;
            {
                float vx[8], vy[8];
                #pragma unroll
                for (int i = 0; i < 8; ++i) {
                    vx[i] = s_px[i * 64 + lane];
                    vy[i] = s_py[i * 64 + lane];
                }
                #pragma unroll
                for (int i = 0; i < 8; ++i) {
                    if (i < n) {
                        const bool wrap = (i + 1 == n);
                        const int  jn   = (i + 1) & 7;
                        const float qx = wrap ? vx[0] : vx[jn];
                        const float qy = wrap ? vy[0] : vy[jn];
                        s += vx[i] * qy - qx * vy[i];
                    }
                }
            }
            const float area = fabsf(0.5f * s);
            if (area > bestA || (area == bestA && p < bestI)) {
                bestA = area; bestI = p;
            }
        }
    }

    // 64-lane (area, min-idx) reduce — order-independent, deterministic
    #pragma unroll
    for (int off = 32; off; off >>= 1) {
        const float oa = __shfl_xor(bestA, off);
        const int   oi = __shfl_xor(bestI, off);
        if (oa > bestA || (oa == bestA && oi < bestI)) { bestA = oa; bestI = oi; }
    }

    const bool matched = (!gt_deg) && (bestA != 0.0f);
    const int label = labels[bg];

    if (matched) {
        const float* sc = scores + (size_t)(b * P_ + bestI) * C_;
        const float v0 = sc[lane];
        const bool  h2 = (lane + 64) < C_;
        const float v1 = h2 ? sc[lane + 64] : -3e38f;
        float bv; int bi;
        if (v1 > v0) { bv = v1; bi = lane + 64; } else { bv = v0; bi = lane; }
        float mx = fmaxf(v0, v1);
        #pragma unroll
        for (int off = 32; off; off >>= 1) mx = fmaxf(mx, __shfl_xor(mx, off));
        #pragma unroll
        for (int off = 32; off; off >>= 1) {
            const float ov2 = __shfl_xor(bv, off);
            const int   oi2 = __shfl_xor(bi, off);
            if (ov2 > bv || (ov2 == bv && oi2 < bi)) { bv = ov2; bi = oi2; }
        }
        float e = expf(v0 - mx) + (h2 ? expf(v1 - mx) : 0.0f);
        #pragma unroll
        for (int off = 32; off; off >>= 1) e += __shfl_xor(e, off);
        if (lane == 0) {
            ce_out[bg]   = mx + logf(e) - sc[label];
            corr_out[bg] = (bi == label) ? 1 : 0;
        }
    } else {
        if (lane == 0) {
            ce_out[bg]   = logf((float)C_);
            corr_out[bg] = 0;
        }
    }
}

// Finalize: deterministic fixed-tree reduction of 1024 (ce, corr) pairs.
__global__ __launch_bounds__(256) void finalize_kernel(
    const float* __restrict__ ce,
    const int*   __restrict__ corr,
    float* __restrict__ out)
{
    const int t = threadIdx.x;
    float a = ce[t] + ce[t + 256] + ce[t + 512] + ce[t + 768];
    int   c = corr[t] + corr[t + 256] + corr[t + 512] + corr[t + 768];
    #pragma unroll
    for (int off = 32; off; off >>= 1) {
        a += __shfl_xor(a, off);
        c += __shfl_xor(c, off);
    }
    __shared__ float pa[4];
    __shared__ int   pc[4];
    if ((t & 63) == 0) { pa[t >> 6] = a; pc[t >> 6] = c; }
    __syncthreads();
    if (t == 0) {
        const float s = (pa[0] + pa[1]) + (pa[2] + pa[3]);
        const int  cc = (pc[0] + pc[1]) + (pc[2] + pc[3]);
        out[0] = s / (float)BG;   // mean ce
        out[1] = (float)BG;       // total_number
        out[2] = (float)cc;       // rec_correct
    }
}

extern "C" void kernel_launch(void* const* d_in, const int* in_sizes, int n_in,
                              void* d_out, int out_size, void* d_ws, size_t ws_size,
                              hipStream_t stream) {
    const float* bboxes = (const float*)d_in[0];   // [B,P,9]
    const float* scores = (const float*)d_in[1];   // [B,P,C]
    const float* polys  = (const float*)d_in[2];   // [B,G,4,2]
    const int*   labels = (const int*)d_in[3];     // [B,G]
    float* out = (float*)d_out;

    float* ce = (float*)d_ws;                             // [BG]
    int*   cr = (int*)((char*)d_ws + BG * sizeof(float)); // [BG]

    match_kernel<<<BG, 256, 0, stream>>>(bboxes, scores, polys, labels, ce, cr);
    finalize_kernel<<<1, 256, 0, stream>>>(ce, cr, out);
}